// Round 6
// baseline (171.205 us; speedup 1.0000x reference)
//
#include <hip/hip_runtime.h>

#define NB_COPY 2048
#define NB_CONV 256
#define NTHR 256

typedef float f4 __attribute__((ext_vector_type(4)));

// ---------------------------------------------------------------------------
// Kernel 1: pure streaming copy of cache -> cache_new (with index-case edits).
// No LDS, tiny VGPR count. stride = 2048*256 = 128*4096 -> residue r = i&4095
// is loop-invariant per thread; total/stride = 32 iterations exactly.
// ---------------------------------------------------------------------------
__global__ __launch_bounds__(256)
void fmc_copy(const float* __restrict__ inputs,
              const float* __restrict__ cache,
              const int* __restrict__ idxp,
              float* __restrict__ cache_out)
{
    const int idx = idxp[0];
    int iw = idx % 64;        if (iw < 0)  iw += 64;
    int iwi = (idx - 1) % 64; if (iwi < 0) iwi += 64;
    const bool upd = (idx - 1) >= 0;   // EXCLUSIVE=True

    const f4* __restrict__ c4 = (const f4*)cache;
    const f4* __restrict__ i4 = (const f4*)inputs;
    f4* __restrict__ o4 = (f4*)cache_out;

    const int t0 = blockIdx.x * NTHR + threadIdx.x;
    const int stride = NB_COPY * NTHR;       // 524288
    const int total = 4096 * 4096;           // f4 count; r-layout: b[12] h[2] w[6] e[4]

    const int r = t0 & 4095;
    const int h = r >> 10, w = (r >> 4) & 63, e = r & 15;

    int kind;            // 0 zero, 1 inputs, 2 cache
    int coff = 0;        // cache read offset (row shift)
    if (!upd)            kind = 2;
    else if (iw != 0)    kind = (h == 3 && w == iwi) ? 1 : 2;               // case A
    else if (iwi != 0) { kind = (h == 2 && w == iwi) ? 1 : (h < 3 ? 2 : 0); // case B
                         coff = 1024; }
    else               { kind = (h == 3) ? (w == 0 ? 1 : 0) : 2;            // case C
                         coff = 1024; }

    if (kind == 2) {
        for (int i = t0; i < total; i += stride)
            o4[i] = c4[i + coff];
    } else if (kind == 1) {              // 16/4096 residues: column from inputs
        for (int i = t0; i < total; i += stride)
            o4[i] = i4[((i >> 12) << 4) + e];
    } else {                             // zero-fill rows (cases B/C)
        const f4 z = (f4)(0.f);
        for (int i = t0; i < total; i += stride)
            o4[i] = z;
    }
}

// ---------------------------------------------------------------------------
// Kernel 2: conv -> y[4096][64].  R1-proven structure: padded LDS (0 bank
// conflicts), 16 batch rows per block, 2b x 4fo register micro-tile.
// ---------------------------------------------------------------------------
__global__ __launch_bounds__(256)
void fmc_conv(const float* __restrict__ inputs,
              const float* __restrict__ cache,
              const float* __restrict__ wk,
              const float* __restrict__ bias,
              const int* __restrict__ idxp,
              float* __restrict__ y_out)
{
    const int idx = idxp[0];
    int iw = idx % 64;        if (iw < 0)  iw += 64;
    int iwi = (idx - 1) % 64; if (iwi < 0) iwi += 64;
    const bool upd = (idx - 1) >= 0;
    const int tid = threadIdx.x;

    __shared__ float Ws[64][68];   // [ci][fo], padded -> conflict-free
    __shared__ float Xs[64][18];   // [ci][b],  padded -> conflict-free
    const int bbase = blockIdx.x * 16;
    const int fog = tid & 15;      // fo group: fo = 4*fog
    const int bp  = tid >> 4;      // compute threads: bp<8 -> b pair

    float acc[2][4];
    if (tid < 128) {
        const f4 bv = *(const f4*)(bias + (fog << 2));
        acc[0][0]=bv.x; acc[0][1]=bv.y; acc[0][2]=bv.z; acc[0][3]=bv.w;
        acc[1][0]=bv.x; acc[1][1]=bv.y; acc[1][2]=bv.z; acc[1][3]=bv.w;
    }

    for (int kh = 0; kh < 4; ++kh) {
        for (int kw = 0; kw < 7; ++kw) {
            if (kh == 3 && kw >= 3) break;          // autoregressive mask
            const int col = iw - 3 + kw;            // window col -> cache col
            int kind;                                // 0 zero, 1 inputs, 2 cache
            int hs = kh;
            if (col < 0 || col >= 64) kind = 0;
            else if (!upd) kind = 2;
            else if (iw != 0) kind = (kh == 3 && col == iwi) ? 1 : 2;   // case A
            else if (iwi != 0) {                                        // case B
                if (kh == 3) kind = 0;
                else if (kh == 2 && col == iwi) kind = 1;
                else { kind = 2; hs = kh + 1; }
            } else {                                                     // case C
                if (kh == 3) kind = (col == 0) ? 1 : 0;
                else { kind = 2; hs = kh + 1; }
            }

            __syncthreads();   // protect LDS from previous tap's readers
            // stage W tap: [ci][fo] 64x64
            const float* wt = wk + (kh * 7 + kw) * 4096;
            #pragma unroll
            for (int i = 0; i < 4; ++i) {
                const int f4i = tid + (i << 8);
                const int ci = f4i >> 4;
                const int fo = (f4i & 15) << 2;
                *(f4*)&Ws[ci][fo] = *(const f4*)(wt + ci * 64 + fo);
            }
            // stage X (transposed): Xs[ci][b]
            {
                const int bl = tid >> 4;
                const int c4i = (tid & 15) << 2;
                f4 v = (f4)(0.f);
                if (kind == 1)
                    v = *(const f4*)(inputs + (bbase + bl) * 64 + c4i);
                else if (kind == 2)
                    v = *(const f4*)(cache + ((((bbase + bl) << 2) + hs) * 64 + col) * 64 + c4i);
                Xs[c4i + 0][bl] = v.x;
                Xs[c4i + 1][bl] = v.y;
                Xs[c4i + 2][bl] = v.z;
                Xs[c4i + 3][bl] = v.w;
            }
            __syncthreads();

            if (tid < 128) {
                #pragma unroll 8
                for (int ci = 0; ci < 64; ++ci) {
                    const f4 w = *(const f4*)&Ws[ci][fog << 2];
                    const float2 x = *(const float2*)&Xs[ci][bp << 1];
                    acc[0][0] = fmaf(x.x, w.x, acc[0][0]);
                    acc[0][1] = fmaf(x.x, w.y, acc[0][1]);
                    acc[0][2] = fmaf(x.x, w.z, acc[0][2]);
                    acc[0][3] = fmaf(x.x, w.w, acc[0][3]);
                    acc[1][0] = fmaf(x.y, w.x, acc[1][0]);
                    acc[1][1] = fmaf(x.y, w.y, acc[1][1]);
                    acc[1][2] = fmaf(x.y, w.z, acc[1][2]);
                    acc[1][3] = fmaf(x.y, w.w, acc[1][3]);
                }
            }
        }
    }
    if (tid < 128) {
        float* y0 = y_out + (bbase + (bp << 1)) * 64 + (fog << 2);
        *(f4*)y0        = (f4){acc[0][0], acc[0][1], acc[0][2], acc[0][3]};
        *(f4*)(y0 + 64) = (f4){acc[1][0], acc[1][1], acc[1][2], acc[1][3]};
    }
}

extern "C" void kernel_launch(void* const* d_in, const int* in_sizes, int n_in,
                              void* d_out, int out_size, void* d_ws, size_t ws_size,
                              hipStream_t stream) {
    const float* inputs = (const float*)d_in[0];
    const float* cache  = (const float*)d_in[1];
    const float* wk     = (const float*)d_in[2];
    const float* bias   = (const float*)d_in[3];
    const int*   idxp   = (const int*)d_in[4];
    float* y_out = (float*)d_out;
    float* cache_out = (float*)d_out + 4096 * 64;

    fmc_copy<<<NB_COPY, NTHR, 0, stream>>>(inputs, cache, idxp, cache_out);
    fmc_conv<<<NB_CONV, NTHR, 0, stream>>>(inputs, cache, wk, bias, idxp, y_out);
}

// Round 7
// 105.627 us; speedup vs baseline: 1.6209x; 1.6209x over previous
//
#include <hip/hip_runtime.h>

#define NB_CONV 256
#define NB_COPY 1536
#define NTHR 256

typedef float f4 __attribute__((ext_vector_type(4)));

// d_out layout: y[4096][64] followed by cache_new[4096][4][64][64]
// R1-proven structure (110.5 us) + ONE lever: nontemporal stores on the
// cache_new write stream (keep loads cached -> preserve L3 read hits).
__global__ __launch_bounds__(256)
void fmc_fused(const float* __restrict__ inputs,
               const float* __restrict__ cache,
               const float* __restrict__ wk,
               const float* __restrict__ bias,
               const int* __restrict__ idxp,
               float* __restrict__ y_out,
               float* __restrict__ cache_out)
{
    const int idx = idxp[0];
    int iw = idx % 64;        if (iw < 0)  iw += 64;
    int iwi = (idx - 1) % 64; if (iwi < 0) iwi += 64;
    const bool upd = (idx - 1) >= 0;   // EXCLUSIVE=True
    const int tid = threadIdx.x;

    if (blockIdx.x < NB_CONV) {
        // ---------------- conv part: y[b][fo] for 16 batch rows ----------------
        __shared__ float Ws[64][68];   // [ci][fo], padded -> conflict-free
        __shared__ float Xs[64][18];   // [ci][b],  padded -> conflict-free
        const int bbase = blockIdx.x * 16;
        const int fog = tid & 15;      // fo group: fo = 4*fog
        const int bp  = tid >> 4;      // compute threads: bp<8 -> b pair

        float acc[2][4];
        if (tid < 128) {
            const f4 bv = *(const f4*)(bias + (fog << 2));
            acc[0][0]=bv.x; acc[0][1]=bv.y; acc[0][2]=bv.z; acc[0][3]=bv.w;
            acc[1][0]=bv.x; acc[1][1]=bv.y; acc[1][2]=bv.z; acc[1][3]=bv.w;
        }

        for (int kh = 0; kh < 4; ++kh) {
            for (int kw = 0; kw < 7; ++kw) {
                if (kh == 3 && kw >= 3) break;          // autoregressive mask
                const int col = iw - 3 + kw;            // window col -> cache col
                int kind;                                // 0 zero, 1 inputs, 2 cache
                int hs = kh;
                if (col < 0 || col >= 64) kind = 0;
                else if (!upd) kind = 2;
                else if (iw != 0) kind = (kh == 3 && col == iwi) ? 1 : 2;   // case A
                else if (iwi != 0) {                                        // case B: shift(add)
                    if (kh == 3) kind = 0;
                    else if (kh == 2 && col == iwi) kind = 1;
                    else { kind = 2; hs = kh + 1; }
                } else {                                                     // case C: add(shift)
                    if (kh == 3) kind = (col == 0) ? 1 : 0;
                    else { kind = 2; hs = kh + 1; }
                }

                __syncthreads();   // protect LDS from previous tap's readers
                // stage W tap: [ci][fo] 64x64
                const float* wt = wk + (kh * 7 + kw) * 4096;
                #pragma unroll
                for (int i = 0; i < 4; ++i) {
                    const int f4i = tid + (i << 8);
                    const int ci = f4i >> 4;
                    const int fo = (f4i & 15) << 2;
                    *(f4*)&Ws[ci][fo] = *(const f4*)(wt + ci * 64 + fo);
                }
                // stage X (transposed): Xs[ci][b]
                {
                    const int bl = tid >> 4;
                    const int c4i = (tid & 15) << 2;
                    f4 v = (f4)(0.f);
                    if (kind == 1)
                        v = *(const f4*)(inputs + (bbase + bl) * 64 + c4i);
                    else if (kind == 2)
                        v = *(const f4*)(cache + ((((bbase + bl) << 2) + hs) * 64 + col) * 64 + c4i);
                    Xs[c4i + 0][bl] = v.x;
                    Xs[c4i + 1][bl] = v.y;
                    Xs[c4i + 2][bl] = v.z;
                    Xs[c4i + 3][bl] = v.w;
                }
                __syncthreads();

                if (tid < 128) {
                    #pragma unroll 16
                    for (int ci = 0; ci < 64; ++ci) {
                        const f4 w = *(const f4*)&Ws[ci][fog << 2];
                        const float2 x = *(const float2*)&Xs[ci][bp << 1];
                        acc[0][0] = fmaf(x.x, w.x, acc[0][0]);
                        acc[0][1] = fmaf(x.x, w.y, acc[0][1]);
                        acc[0][2] = fmaf(x.x, w.z, acc[0][2]);
                        acc[0][3] = fmaf(x.x, w.w, acc[0][3]);
                        acc[1][0] = fmaf(x.y, w.x, acc[1][0]);
                        acc[1][1] = fmaf(x.y, w.y, acc[1][1]);
                        acc[1][2] = fmaf(x.y, w.z, acc[1][2]);
                        acc[1][3] = fmaf(x.y, w.w, acc[1][3]);
                    }
                }
            }
        }
        if (tid < 128) {
            float* y0 = y_out + (bbase + (bp << 1)) * 64 + (fog << 2);
            *(f4*)y0        = (f4){acc[0][0], acc[0][1], acc[0][2], acc[0][3]};
            *(f4*)(y0 + 64) = (f4){acc[1][0], acc[1][1], acc[1][2], acc[1][3]};
        }
    } else {
        // ---------------- copy part: cache_new (R1 branchy loop, NT stores) ----
        const f4* __restrict__ c4 = (const f4*)cache;
        const f4* __restrict__ i4 = (const f4*)inputs;
        f4* __restrict__ o4 = (f4*)cache_out;
        const int t0 = (blockIdx.x - NB_CONV) * NTHR + tid;
        const int stride = NB_COPY * NTHR;
        const int total = 4096 * 4096;   // 16,777,216 float4
        if (!upd) {
            for (int i = t0; i < total; i += stride)
                __builtin_nontemporal_store(c4[i], o4 + i);
        } else if (iw != 0) {            // case A: plain copy + column override
            const int target = 3 * 1024 + iwi * 16;
            for (int i = t0; i < total; i += stride) {
                const int r = i & 4095;
                const f4* src = c4 + i;
                if ((r & ~15) == target)                       // h==3 && w==iwi
                    src = i4 + ((i >> 12) << 4) + (r & 15);
                __builtin_nontemporal_store(*src, o4 + i);
            }
        } else if (iwi != 0) {           // case B: shift rows up, insert at (2,iwi), zero row 3
            for (int i = t0; i < total; i += stride) {
                const int r = i & 4095;
                const int h = r >> 10;
                f4 v = (f4)(0.f);
                if (h == 2 && ((r >> 4) & 63) == iwi) v = i4[((i >> 12) << 4) + (r & 15)];
                else if (h < 3) v = c4[i + 1024];
                __builtin_nontemporal_store(v, o4 + i);
            }
        } else {                         // case C: shift rows up, row 3 = inputs at col 0 else 0
            for (int i = t0; i < total; i += stride) {
                const int r = i & 4095;
                const int h = r >> 10;
                f4 v = (f4)(0.f);
                if (h == 3) { if (((r >> 4) & 63) == 0) v = i4[((i >> 12) << 4) + (r & 15)]; }
                else v = c4[i + 1024];
                __builtin_nontemporal_store(v, o4 + i);
            }
        }
    }
}

extern "C" void kernel_launch(void* const* d_in, const int* in_sizes, int n_in,
                              void* d_out, int out_size, void* d_ws, size_t ws_size,
                              hipStream_t stream) {
    const float* inputs = (const float*)d_in[0];
    const float* cache  = (const float*)d_in[1];
    const float* wk     = (const float*)d_in[2];
    const float* bias   = (const float*)d_in[3];
    const int*   idxp   = (const int*)d_in[4];
    float* y_out = (float*)d_out;
    float* cache_out = (float*)d_out + 4096 * 64;
    fmc_fused<<<NB_CONV + NB_COPY, NTHR, 0, stream>>>(inputs, cache, wk, bias, idxp,
                                                      y_out, cache_out);
}

// Round 8
// 103.561 us; speedup vs baseline: 1.6532x; 1.0199x over previous
//
#include <hip/hip_runtime.h>

#define NB_CONV 256
#define NB_COPY 1792   // R8 lever: 256 extra copy blocks backfill retired conv slots
#define NTHR 256

typedef float f4 __attribute__((ext_vector_type(4)));

// d_out layout: y[4096][64] followed by cache_new[4096][4][64][64]
// R7-proven structure (105.6 us): R1 fused kernel + NT stores on cache_new.
__global__ __launch_bounds__(256)
void fmc_fused(const float* __restrict__ inputs,
               const float* __restrict__ cache,
               const float* __restrict__ wk,
               const float* __restrict__ bias,
               const int* __restrict__ idxp,
               float* __restrict__ y_out,
               float* __restrict__ cache_out)
{
    const int idx = idxp[0];
    int iw = idx % 64;        if (iw < 0)  iw += 64;
    int iwi = (idx - 1) % 64; if (iwi < 0) iwi += 64;
    const bool upd = (idx - 1) >= 0;   // EXCLUSIVE=True
    const int tid = threadIdx.x;

    if (blockIdx.x < NB_CONV) {
        // ---------------- conv part: y[b][fo] for 16 batch rows ----------------
        __shared__ float Ws[64][68];   // [ci][fo], padded -> conflict-free
        __shared__ float Xs[64][18];   // [ci][b],  padded -> conflict-free
        const int bbase = blockIdx.x * 16;
        const int fog = tid & 15;      // fo group: fo = 4*fog
        const int bp  = tid >> 4;      // compute threads: bp<8 -> b pair

        float acc[2][4];
        if (tid < 128) {
            const f4 bv = *(const f4*)(bias + (fog << 2));
            acc[0][0]=bv.x; acc[0][1]=bv.y; acc[0][2]=bv.z; acc[0][3]=bv.w;
            acc[1][0]=bv.x; acc[1][1]=bv.y; acc[1][2]=bv.z; acc[1][3]=bv.w;
        }

        for (int kh = 0; kh < 4; ++kh) {
            for (int kw = 0; kw < 7; ++kw) {
                if (kh == 3 && kw >= 3) break;          // autoregressive mask
                const int col = iw - 3 + kw;            // window col -> cache col
                int kind;                                // 0 zero, 1 inputs, 2 cache
                int hs = kh;
                if (col < 0 || col >= 64) kind = 0;
                else if (!upd) kind = 2;
                else if (iw != 0) kind = (kh == 3 && col == iwi) ? 1 : 2;   // case A
                else if (iwi != 0) {                                        // case B: shift(add)
                    if (kh == 3) kind = 0;
                    else if (kh == 2 && col == iwi) kind = 1;
                    else { kind = 2; hs = kh + 1; }
                } else {                                                     // case C: add(shift)
                    if (kh == 3) kind = (col == 0) ? 1 : 0;
                    else { kind = 2; hs = kh + 1; }
                }

                __syncthreads();   // protect LDS from previous tap's readers
                // stage W tap: [ci][fo] 64x64
                const float* wt = wk + (kh * 7 + kw) * 4096;
                #pragma unroll
                for (int i = 0; i < 4; ++i) {
                    const int f4i = tid + (i << 8);
                    const int ci = f4i >> 4;
                    const int fo = (f4i & 15) << 2;
                    *(f4*)&Ws[ci][fo] = *(const f4*)(wt + ci * 64 + fo);
                }
                // stage X (transposed): Xs[ci][b]
                {
                    const int bl = tid >> 4;
                    const int c4i = (tid & 15) << 2;
                    f4 v = (f4)(0.f);
                    if (kind == 1)
                        v = *(const f4*)(inputs + (bbase + bl) * 64 + c4i);
                    else if (kind == 2)
                        v = *(const f4*)(cache + ((((bbase + bl) << 2) + hs) * 64 + col) * 64 + c4i);
                    Xs[c4i + 0][bl] = v.x;
                    Xs[c4i + 1][bl] = v.y;
                    Xs[c4i + 2][bl] = v.z;
                    Xs[c4i + 3][bl] = v.w;
                }
                __syncthreads();

                if (tid < 128) {
                    #pragma unroll 16
                    for (int ci = 0; ci < 64; ++ci) {
                        const f4 w = *(const f4*)&Ws[ci][fog << 2];
                        const float2 x = *(const float2*)&Xs[ci][bp << 1];
                        acc[0][0] = fmaf(x.x, w.x, acc[0][0]);
                        acc[0][1] = fmaf(x.x, w.y, acc[0][1]);
                        acc[0][2] = fmaf(x.x, w.z, acc[0][2]);
                        acc[0][3] = fmaf(x.x, w.w, acc[0][3]);
                        acc[1][0] = fmaf(x.y, w.x, acc[1][0]);
                        acc[1][1] = fmaf(x.y, w.y, acc[1][1]);
                        acc[1][2] = fmaf(x.y, w.z, acc[1][2]);
                        acc[1][3] = fmaf(x.y, w.w, acc[1][3]);
                    }
                }
            }
        }
        if (tid < 128) {
            float* y0 = y_out + (bbase + (bp << 1)) * 64 + (fog << 2);
            *(f4*)y0        = (f4){acc[0][0], acc[0][1], acc[0][2], acc[0][3]};
            *(f4*)(y0 + 64) = (f4){acc[1][0], acc[1][1], acc[1][2], acc[1][3]};
        }
    } else {
        // ---------------- copy part: cache_new (R1 branchy loop, NT stores) ----
        const f4* __restrict__ c4 = (const f4*)cache;
        const f4* __restrict__ i4 = (const f4*)inputs;
        f4* __restrict__ o4 = (f4*)cache_out;
        const int t0 = (blockIdx.x - NB_CONV) * NTHR + tid;
        const int stride = NB_COPY * NTHR;
        const int total = 4096 * 4096;   // 16,777,216 float4
        if (!upd) {
            for (int i = t0; i < total; i += stride)
                __builtin_nontemporal_store(c4[i], o4 + i);
        } else if (iw != 0) {            // case A: plain copy + column override
            const int target = 3 * 1024 + iwi * 16;
            for (int i = t0; i < total; i += stride) {
                const int r = i & 4095;
                const f4* src = c4 + i;
                if ((r & ~15) == target)                       // h==3 && w==iwi
                    src = i4 + ((i >> 12) << 4) + (r & 15);
                __builtin_nontemporal_store(*src, o4 + i);
            }
        } else if (iwi != 0) {           // case B: shift rows up, insert at (2,iwi), zero row 3
            for (int i = t0; i < total; i += stride) {
                const int r = i & 4095;
                const int h = r >> 10;
                f4 v = (f4)(0.f);
                if (h == 2 && ((r >> 4) & 63) == iwi) v = i4[((i >> 12) << 4) + (r & 15)];
                else if (h < 3) v = c4[i + 1024];
                __builtin_nontemporal_store(v, o4 + i);
            }
        } else {                         // case C: shift rows up, row 3 = inputs at col 0 else 0
            for (int i = t0; i < total; i += stride) {
                const int r = i & 4095;
                const int h = r >> 10;
                f4 v = (f4)(0.f);
                if (h == 3) { if (((r >> 4) & 63) == 0) v = i4[((i >> 12) << 4) + (r & 15)]; }
                else v = c4[i + 1024];
                __builtin_nontemporal_store(v, o4 + i);
            }
        }
    }
}

extern "C" void kernel_launch(void* const* d_in, const int* in_sizes, int n_in,
                              void* d_out, int out_size, void* d_ws, size_t ws_size,
                              hipStream_t stream) {
    const float* inputs = (const float*)d_in[0];
    const float* cache  = (const float*)d_in[1];
    const float* wk     = (const float*)d_in[2];
    const float* bias   = (const float*)d_in[3];
    const int*   idxp   = (const int*)d_in[4];
    float* y_out = (float*)d_out;
    float* cache_out = (float*)d_out + 4096 * 64;
    fmc_fused<<<NB_CONV + NB_COPY, NTHR, 0, stream>>>(inputs, cache, wk, bias, idxp,
                                                      y_out, cache_out);
}